// Round 1
// 715.065 us; speedup vs baseline: 1.4430x; 1.4430x over previous
//
#include <hip/hip_runtime.h>
#include <hip/hip_bf16.h>

#define E_CNT 800000
#define N_CNT 50000
#define E_TILES (E_CNT / 16)   // 50000
#define N_TILES (N_CNT / 16)   // 3125
#define SCAN_BLOCKS 196        // ceil(50000 / 256)

// ---- workspace layout (bytes) ----
// counts[50000]   @ 0        (zeroed by memset; histogram of dst degrees)
// offsets[50000]  @ 204800   (exclusive scan of counts)
// cursor[50000]   @ 409600   (running fill cursor for scatter)
// bsum[196]       @ 614400   (per-scan-block sums -> exclusive block offsets)
// edge_ids[800000]@ 615424   (edge ids grouped by dst = CSR payload)
#define WS_COUNTS  0
#define WS_OFFSETS 204800
#define WS_CURSOR  409600
#define WS_BSUM    614400
#define WS_EIDS    615424

typedef __attribute__((ext_vector_type(8))) short bf16x8;   // MFMA A/B frag (8 bf16)
typedef __attribute__((ext_vector_type(4))) short short4v;  // 4 bf16 packed store
typedef __attribute__((ext_vector_type(4))) float f32x4;    // MFMA C/D frag / float4

static __device__ __forceinline__ short f2bf(float v) {
    union { __hip_bfloat16 b; short u; } cv;
    cv.b = __float2bfloat16(v);
    return cv.u;
}

// ---------------- CSR build: histogram -> scan -> scatter ----------------

__global__ void hist_kernel(const int* __restrict__ eidx, int* __restrict__ counts) {
    int stride = gridDim.x * blockDim.x;
    for (int i = blockIdx.x * blockDim.x + threadIdx.x; i < E_CNT; i += stride) {
        int d = eidx[E_CNT + i];
        if ((unsigned)d >= (unsigned)N_CNT) d = 0;
        atomicAdd(&counts[d], 1);
    }
}

__global__ void scan_block_sums(const int* __restrict__ counts, int* __restrict__ bsum) {
    __shared__ int s[256];
    int t = threadIdx.x;
    int i = blockIdx.x * 256 + t;
    s[t] = (i < N_CNT) ? counts[i] : 0;
    __syncthreads();
    #pragma unroll
    for (int off = 128; off; off >>= 1) {
        if (t < off) s[t] += s[t + off];
        __syncthreads();
    }
    if (t == 0) bsum[blockIdx.x] = s[0];
}

// exclusive scan of the 196 block sums, in place (single block)
__global__ void scan_top(int* __restrict__ bsum) {
    __shared__ int s[256];
    int t = threadIdx.x;
    int mine = (t < SCAN_BLOCKS) ? bsum[t] : 0;
    s[t] = mine;
    __syncthreads();
    #pragma unroll
    for (int off = 1; off < 256; off <<= 1) {
        int v = (t >= off) ? s[t - off] : 0;
        __syncthreads();
        s[t] += v;
        __syncthreads();
    }
    if (t < SCAN_BLOCKS) bsum[t] = s[t] - mine;   // inclusive -> exclusive
}

__global__ void scan_within(const int* __restrict__ counts, const int* __restrict__ bsum,
                            int* __restrict__ offsets, int* __restrict__ cursor) {
    __shared__ int s[256];
    int t = threadIdx.x;
    int i = blockIdx.x * 256 + t;
    int mine = (i < N_CNT) ? counts[i] : 0;
    s[t] = mine;
    __syncthreads();
    #pragma unroll
    for (int off = 1; off < 256; off <<= 1) {
        int v = (t >= off) ? s[t - off] : 0;
        __syncthreads();
        s[t] += v;
        __syncthreads();
    }
    if (i < N_CNT) {
        int o = bsum[blockIdx.x] + s[t] - mine;   // exclusive prefix
        offsets[i] = o;
        cursor[i]  = o;
    }
}

__global__ void scatter_kernel(const int* __restrict__ eidx, int* __restrict__ cursor,
                               int* __restrict__ edge_ids) {
    int stride = gridDim.x * blockDim.x;
    for (int i = blockIdx.x * blockDim.x + threadIdx.x; i < E_CNT; i += stride) {
        int d = eidx[E_CNT + i];
        if ((unsigned)d >= (unsigned)N_CNT) d = 0;
        int pos = atomicAdd(&cursor[d], 1);
        edge_ids[pos] = i;
    }
}

// ---------------- edge kernel: MLP only, NO atomics ----------------
// Structure: 4 waves cooperate on one 16-edge tile; grid-stride over tiles.
// Swapped-operand MFMA: GEMM1 h^T = W1^T(A,regs) * edge_in^T(B,LDS), K=192;
// GEMM2 out^T = W2^T(A,regs) * h^T(B,LDS), K=128.
__launch_bounds__(256, 2)
__global__ void edge_kernel(const float* __restrict__ x,
                            const int* __restrict__ eidx,
                            const float* __restrict__ eattr,
                            const float* __restrict__ w1, const float* __restrict__ b1,
                            const float* __restrict__ w2, const float* __restrict__ b2,
                            float* __restrict__ eout) {
    __shared__ short s_in[16][200];   // edge_in rows bf16 (192 + 8 pad)
    __shared__ short s_h[16][136];    // h rows bf16 (128 + 8 pad)

    const int tid  = threadIdx.x;
    const int wave = tid >> 6;
    const int l15  = tid & 15;
    const int q    = (tid & 63) >> 4;

    // ---- weight fragments -> registers (once per block), fp32 -> bf16 ----
    bf16x8 a1[2][6];
    #pragma unroll
    for (int t = 0; t < 2; t++)
        #pragma unroll
        for (int k0 = 0; k0 < 6; k0++)
            #pragma unroll
            for (int j = 0; j < 8; j++)
                a1[t][k0][j] = f2bf(w1[(k0 * 32 + q * 8 + j) * 128 + (wave * 32 + t * 16 + l15)]);
    bf16x8 a2[4];
    #pragma unroll
    for (int k0 = 0; k0 < 4; k0++)
        #pragma unroll
        for (int j = 0; j < 8; j++)
            a2[k0][j] = f2bf(w2[(k0 * 32 + q * 8 + j) * 64 + (wave * 16 + l15)]);
    f32x4 bias1[2];
    #pragma unroll
    for (int t = 0; t < 2; t++)
        #pragma unroll
        for (int r = 0; r < 4; r++)
            bias1[t][r] = b1[wave * 32 + t * 16 + q * 4 + r];
    f32x4 bias2;
    #pragma unroll
    for (int r = 0; r < 4; r++) bias2[r] = b2[wave * 16 + q * 4 + r];

    for (int tile = blockIdx.x; tile < E_TILES; tile += gridDim.x) {
        const int e0 = tile * 16;

        // stage edge_in = [eattr | x[src] | x[dst]]: 16 rows x 48 float4-chunks,
        // fp32 global -> bf16 LDS
        #pragma unroll
        for (int i = 0; i < 3; i++) {
            int c  = tid + 256 * i;            // 0..767
            int el = c / 48, p = c - el * 48;  // p = float4 index in 192-float row
            const float* src;
            if (p < 16) {
                src = eattr + (long)(e0 + el) * 64 + p * 4;
            } else {
                int id = eidx[(p < 32 ? 0 : E_CNT) + e0 + el];
                if ((unsigned)id >= (unsigned)N_CNT) id = 0;
                src = x + (long)id * 64 + ((p - 16) & 15) * 4;
            }
            f32x4 v = *(const f32x4*)src;
            short4v pk = { f2bf(v[0]), f2bf(v[1]), f2bf(v[2]), f2bf(v[3]) };
            *(short4v*)&s_in[el][p * 4] = pk;
        }
        __syncthreads();

        // GEMM1: 12 MFMA/wave
        f32x4 acc1[2];
        acc1[0] = (f32x4){0.f, 0.f, 0.f, 0.f};
        acc1[1] = (f32x4){0.f, 0.f, 0.f, 0.f};
        #pragma unroll
        for (int k0 = 0; k0 < 6; k0++) {
            bf16x8 bfrag = *(const bf16x8*)&s_in[l15][k0 * 32 + q * 8];
            acc1[0] = __builtin_amdgcn_mfma_f32_16x16x32_bf16(a1[0][k0], bfrag, acc1[0], 0, 0, 0);
            acc1[1] = __builtin_amdgcn_mfma_f32_16x16x32_bf16(a1[1][k0], bfrag, acc1[1], 0, 0, 0);
        }
        // bias+relu, write h (D: col=edge l15, row=hidden wave*32+t*16+q*4+r)
        #pragma unroll
        for (int t = 0; t < 2; t++) {
            int hid = wave * 32 + t * 16 + q * 4;
            short4v pk = { f2bf(fmaxf(acc1[t][0] + bias1[t][0], 0.f)),
                           f2bf(fmaxf(acc1[t][1] + bias1[t][1], 0.f)),
                           f2bf(fmaxf(acc1[t][2] + bias1[t][2], 0.f)),
                           f2bf(fmaxf(acc1[t][3] + bias1[t][3], 0.f)) };
            *(short4v*)&s_h[l15][hid] = pk;
        }
        __syncthreads();

        // GEMM2: 4 MFMA/wave
        f32x4 acc2 = (f32x4){0.f, 0.f, 0.f, 0.f};
        #pragma unroll
        for (int k0 = 0; k0 < 4; k0++) {
            bf16x8 bfrag = *(const bf16x8*)&s_h[l15][k0 * 32 + q * 8];
            acc2 = __builtin_amdgcn_mfma_f32_16x16x32_bf16(a2[k0], bfrag, acc2, 0, 0, 0);
        }

        // epilogue: fp32 eout store only (scatter handled by CSR gather in node pass)
        f32x4 out;
        out[0] = acc2[0] + bias2[0];
        out[1] = acc2[1] + bias2[1];
        out[2] = acc2[2] + bias2[2];
        out[3] = acc2[3] + bias2[3];
        *(f32x4*)&eout[(long)(e0 + l15) * 64 + wave * 16 + q * 4] = out;
        __syncthreads();   // protect s_in/s_h reuse next iteration
    }
}

// ---------------- node kernel: CSR gather-sum + MLP ----------------
// messages[n] = sum over edges with dst==n of eout[e]; computed on the fly by
// 16-thread groups (group g = node g of the tile, lane c = float4 chunk c).
__launch_bounds__(256, 2)
__global__ void node_kernel(const float* __restrict__ x,
                            const float* __restrict__ eout,
                            const int* __restrict__ offsets,
                            const int* __restrict__ counts,
                            const int* __restrict__ edge_ids,
                            const float* __restrict__ w1, const float* __restrict__ b1,
                            const float* __restrict__ w2, const float* __restrict__ b2,
                            float* __restrict__ xout) {
    __shared__ short s_in[16][136];
    __shared__ short s_h[16][136];

    const int tid  = threadIdx.x;
    const int wave = tid >> 6;
    const int l15  = tid & 15;
    const int q    = (tid & 63) >> 4;

    bf16x8 a1[2][4];
    #pragma unroll
    for (int t = 0; t < 2; t++)
        #pragma unroll
        for (int k0 = 0; k0 < 4; k0++)
            #pragma unroll
            for (int j = 0; j < 8; j++)
                a1[t][k0][j] = f2bf(w1[(k0 * 32 + q * 8 + j) * 128 + (wave * 32 + t * 16 + l15)]);
    bf16x8 a2[4];
    #pragma unroll
    for (int k0 = 0; k0 < 4; k0++)
        #pragma unroll
        for (int j = 0; j < 8; j++)
            a2[k0][j] = f2bf(w2[(k0 * 32 + q * 8 + j) * 64 + (wave * 16 + l15)]);
    f32x4 bias1[2];
    #pragma unroll
    for (int t = 0; t < 2; t++)
        #pragma unroll
        for (int r = 0; r < 4; r++)
            bias1[t][r] = b1[wave * 32 + t * 16 + q * 4 + r];
    f32x4 bias2;
    #pragma unroll
    for (int r = 0; r < 4; r++) bias2[r] = b2[wave * 16 + q * 4 + r];

    const int gel = tid >> 4;   // node-in-tile this thread gathers for
    const int gc  = tid & 15;   // float4 chunk (0..15) of the 64-float row

    for (int tile = blockIdx.x; tile < N_TILES; tile += gridDim.x) {
        const int n0 = tile * 16;
        const int n  = n0 + gel;

        // stage x[n] -> s_in[:, 0:64] (one float4 chunk per thread)
        {
            f32x4 v = *(const f32x4*)(x + (long)n * 64 + gc * 4);
            short4v pk = { f2bf(v[0]), f2bf(v[1]), f2bf(v[2]), f2bf(v[3]) };
            *(short4v*)&s_in[gel][gc * 4] = pk;
        }

        // gather-sum messages[n] -> s_in[:, 64:128]
        {
            int beg = offsets[n];
            int deg = counts[n];
            f32x4 acc = (f32x4){0.f, 0.f, 0.f, 0.f};
            int j = 0;
            // 4-deep software pipeline to overlap the dependent eid->row loads
            for (; j + 4 <= deg; j += 4) {
                int e0i = edge_ids[beg + j + 0];
                int e1i = edge_ids[beg + j + 1];
                int e2i = edge_ids[beg + j + 2];
                int e3i = edge_ids[beg + j + 3];
                f32x4 v0 = *(const f32x4*)(eout + (long)e0i * 64 + gc * 4);
                f32x4 v1 = *(const f32x4*)(eout + (long)e1i * 64 + gc * 4);
                f32x4 v2 = *(const f32x4*)(eout + (long)e2i * 64 + gc * 4);
                f32x4 v3 = *(const f32x4*)(eout + (long)e3i * 64 + gc * 4);
                #pragma unroll
                for (int r = 0; r < 4; r++) acc[r] += v0[r] + v1[r] + v2[r] + v3[r];
            }
            for (; j < deg; j++) {
                int ei = edge_ids[beg + j];
                f32x4 v = *(const f32x4*)(eout + (long)ei * 64 + gc * 4);
                #pragma unroll
                for (int r = 0; r < 4; r++) acc[r] += v[r];
            }
            short4v pk = { f2bf(acc[0]), f2bf(acc[1]), f2bf(acc[2]), f2bf(acc[3]) };
            *(short4v*)&s_in[gel][64 + gc * 4] = pk;
        }
        __syncthreads();

        f32x4 acc1[2];
        acc1[0] = (f32x4){0.f, 0.f, 0.f, 0.f};
        acc1[1] = (f32x4){0.f, 0.f, 0.f, 0.f};
        #pragma unroll
        for (int k0 = 0; k0 < 4; k0++) {
            bf16x8 bfrag = *(const bf16x8*)&s_in[l15][k0 * 32 + q * 8];
            acc1[0] = __builtin_amdgcn_mfma_f32_16x16x32_bf16(a1[0][k0], bfrag, acc1[0], 0, 0, 0);
            acc1[1] = __builtin_amdgcn_mfma_f32_16x16x32_bf16(a1[1][k0], bfrag, acc1[1], 0, 0, 0);
        }
        #pragma unroll
        for (int t = 0; t < 2; t++) {
            int hid = wave * 32 + t * 16 + q * 4;
            short4v pk = { f2bf(fmaxf(acc1[t][0] + bias1[t][0], 0.f)),
                           f2bf(fmaxf(acc1[t][1] + bias1[t][1], 0.f)),
                           f2bf(fmaxf(acc1[t][2] + bias1[t][2], 0.f)),
                           f2bf(fmaxf(acc1[t][3] + bias1[t][3], 0.f)) };
            *(short4v*)&s_h[l15][hid] = pk;
        }
        __syncthreads();

        f32x4 acc2 = (f32x4){0.f, 0.f, 0.f, 0.f};
        #pragma unroll
        for (int k0 = 0; k0 < 4; k0++) {
            bf16x8 bfrag = *(const bf16x8*)&s_h[l15][k0 * 32 + q * 8];
            acc2 = __builtin_amdgcn_mfma_f32_16x16x32_bf16(a2[k0], bfrag, acc2, 0, 0, 0);
        }
        f32x4 out;
        out[0] = acc2[0] + bias2[0];
        out[1] = acc2[1] + bias2[1];
        out[2] = acc2[2] + bias2[2];
        out[3] = acc2[3] + bias2[3];
        *(f32x4*)&xout[(long)(n0 + l15) * 64 + wave * 16 + q * 4] = out;
        __syncthreads();
    }
}

extern "C" void kernel_launch(void* const* d_in, const int* in_sizes, int n_in,
                              void* d_out, int out_size, void* d_ws, size_t ws_size,
                              hipStream_t stream) {
    const float* x     = (const float*)d_in[0];
    const int*   eidx  = (const int*)d_in[1];
    const float* eattr = (const float*)d_in[2];
    const float* eW1   = (const float*)d_in[3];
    const float* eb1   = (const float*)d_in[4];
    const float* eW2   = (const float*)d_in[5];
    const float* eb2   = (const float*)d_in[6];
    const float* nW1   = (const float*)d_in[7];
    const float* nb1   = (const float*)d_in[8];
    const float* nW2   = (const float*)d_in[9];
    const float* nb2   = (const float*)d_in[10];

    char* ws = (char*)d_ws;
    int* counts   = (int*)(ws + WS_COUNTS);
    int* offsets  = (int*)(ws + WS_OFFSETS);
    int* cursor   = (int*)(ws + WS_CURSOR);
    int* bsum     = (int*)(ws + WS_BSUM);
    int* edge_ids = (int*)(ws + WS_EIDS);

    float* xout = (float*)d_out;
    float* eout = xout + (long)N_CNT * 64;

    hipMemsetAsync(counts, 0, 204800, stream);
    hist_kernel<<<1024, 256, 0, stream>>>(eidx, counts);
    scan_block_sums<<<SCAN_BLOCKS, 256, 0, stream>>>(counts, bsum);
    scan_top<<<1, 256, 0, stream>>>(bsum);
    scan_within<<<SCAN_BLOCKS, 256, 0, stream>>>(counts, bsum, offsets, cursor);
    scatter_kernel<<<1024, 256, 0, stream>>>(eidx, cursor, edge_ids);

    edge_kernel<<<2048, 256, 0, stream>>>(x, eidx, eattr, eW1, eb1, eW2, eb2, eout);
    node_kernel<<<1024, 256, 0, stream>>>(x, eout, offsets, counts, edge_ids,
                                          nW1, nb1, nW2, nb2, xout);
}